// Round 2
// baseline (81.524 us; speedup 1.0000x reference)
//
#include <hip/hip_runtime.h>

#define NG 2
#define NV 320
#define GV 640      // NG*NV
#define DHALF 128   // CODE_DIM/NG
#define BSROWS 2048 // B*S
#define NROWS 4096  // BSROWS*NG
#define K_DIM 512

typedef _Float16 half8 __attribute__((ext_vector_type(8)));
typedef _Float16 half4 __attribute__((ext_vector_type(4)));
typedef float floatx4 __attribute__((ext_vector_type(4)));

#define MFMA16(a, b, c) __builtin_amdgcn_mfma_f32_16x16x32_f16(a, b, c, 0, 0, 0)

// ---------------- Prep: W[512][640] f32 -> Wt_h/Wt_l [640][512] f16, scale 1024 -----------
__global__ __launch_bounds__(256) void prep_w_kernel(
    const float* __restrict__ W, _Float16* __restrict__ Wth, _Float16* __restrict__ Wtl) {
  __shared__ float T[32][33];
  const int k0 = blockIdx.y * 32, n0 = blockIdx.x * 32;
  const int t = threadIdx.x;
  const int r = t >> 3, c4 = (t & 7) << 2;
  float4 v = *(const float4*)(W + (k0 + r) * GV + n0 + c4);
  T[r][c4 + 0] = v.x; T[r][c4 + 1] = v.y; T[r][c4 + 2] = v.z; T[r][c4 + 3] = v.w;
  __syncthreads();
  const int nr = t >> 3, k4 = (t & 7) << 2;
  half4 hv, lv;
#pragma unroll
  for (int j = 0; j < 4; ++j) {
    float s = T[k4 + j][nr] * 1024.0f;
    _Float16 h = (_Float16)s;
    hv[j] = h;
    lv[j] = (_Float16)(s - (float)h);
  }
  *(half4*)(Wth + (n0 + nr) * K_DIM + k0 + k4) = hv;
  *(half4*)(Wtl + (n0 + nr) * K_DIM + k0 + k4) = lv;
}

// ---------------- GEMM: logits = x @ W + b via f16x2-split MFMA ---------------------------
// Block 64x64 tile, 4 waves, each wave one 32x32 sub-tile. BK=32.
#define LDAs 40  // f16 per LDS row (32 + 8 pad); 80 B, 16B-aligned

__global__ __launch_bounds__(256) void gemm_mfma_kernel(
    const float* __restrict__ X, const _Float16* __restrict__ Wth,
    const _Float16* __restrict__ Wtl, const float* __restrict__ bias,
    float* __restrict__ C) {
  __shared__ _Float16 Ah[64 * LDAs], Al[64 * LDAs], Bh[64 * LDAs], Bl[64 * LDAs];
  const int tid = threadIdx.x;
  const int bm = blockIdx.y * 64, bn = blockIdx.x * 64;
  const int w = tid >> 6, lane = tid & 63;
  const int wr = w >> 1, wc = w & 1;

  // staging: thread -> (row 0..63, k-chunk of 8)
  const int srow = tid >> 2;
  const int skc = (tid & 3) << 3;
  const float* Xg = X + (bm + srow) * K_DIM + skc;
  const _Float16* Bhg = Wth + (bn + srow) * K_DIM + skc;
  const _Float16* Blg = Wtl + (bn + srow) * K_DIM + skc;
  const int sA = srow * LDAs + skc;

  // fragment read offsets
  const int frow = lane & 15;
  const int fkg = (lane >> 4) << 3;
  const int a0o = (wr * 32 + frow) * LDAs + fkg;
  const int b0o = (wc * 32 + frow) * LDAs + fkg;

  floatx4 acc[2][2] = {};

  for (int k0 = 0; k0 < K_DIM; k0 += 32) {
    float4 xa = *(const float4*)(Xg + k0);
    float4 xb = *(const float4*)(Xg + k0 + 4);
    half8 bhv = *(const half8*)(Bhg + k0);
    half8 blv = *(const half8*)(Blg + k0);
    __syncthreads();  // previous iter's reads done before overwrite
    float xv[8] = {xa.x, xa.y, xa.z, xa.w, xb.x, xb.y, xb.z, xb.w};
    half8 hv, lv;
#pragma unroll
    for (int j = 0; j < 8; ++j) {
      float s = xv[j] * 64.0f;
      _Float16 h = (_Float16)s;
      hv[j] = h;
      lv[j] = (_Float16)(s - (float)h);
    }
    *(half8*)&Ah[sA] = hv;
    *(half8*)&Al[sA] = lv;
    *(half8*)&Bh[sA] = bhv;
    *(half8*)&Bl[sA] = blv;
    __syncthreads();

    half8 ah0 = *(const half8*)&Ah[a0o];
    half8 ah1 = *(const half8*)&Ah[a0o + 16 * LDAs];
    half8 al0 = *(const half8*)&Al[a0o];
    half8 al1 = *(const half8*)&Al[a0o + 16 * LDAs];
    half8 bh0 = *(const half8*)&Bh[b0o];
    half8 bh1 = *(const half8*)&Bh[b0o + 16 * LDAs];
    half8 bl0 = *(const half8*)&Bl[b0o];
    half8 bl1 = *(const half8*)&Bl[b0o + 16 * LDAs];

    // hh
    acc[0][0] = MFMA16(ah0, bh0, acc[0][0]);
    acc[0][1] = MFMA16(ah0, bh1, acc[0][1]);
    acc[1][0] = MFMA16(ah1, bh0, acc[1][0]);
    acc[1][1] = MFMA16(ah1, bh1, acc[1][1]);
    // hl
    acc[0][0] = MFMA16(ah0, bl0, acc[0][0]);
    acc[0][1] = MFMA16(ah0, bl1, acc[0][1]);
    acc[1][0] = MFMA16(ah1, bl0, acc[1][0]);
    acc[1][1] = MFMA16(ah1, bl1, acc[1][1]);
    // lh
    acc[0][0] = MFMA16(al0, bh0, acc[0][0]);
    acc[0][1] = MFMA16(al0, bh1, acc[0][1]);
    acc[1][0] = MFMA16(al1, bh0, acc[1][0]);
    acc[1][1] = MFMA16(al1, bh1, acc[1][1]);
  }

  // epilogue: C/D layout: col = lane&15, row = (lane>>4)*4 + reg
  const float inv = 1.0f / 65536.0f;
#pragma unroll
  for (int i = 0; i < 2; ++i)
#pragma unroll
    for (int j = 0; j < 2; ++j) {
      const int col = bn + wc * 32 + j * 16 + (lane & 15);
      const int r0 = bm + wr * 32 + i * 16 + ((lane >> 4) << 2);
      const float bb = bias[col];
#pragma unroll
      for (int q = 0; q < 4; ++q)
        C[(r0 + q) * GV + col] = acc[i][j][q] * inv + bb;
    }
}

// ---------------- Row kernel: per row of [4096,320]: argmax(l+g) + softmax(l) marginals ----
__global__ __launch_bounds__(256) void row_kernel(
    const float* __restrict__ logits, const float* __restrict__ gumbels,
    int* __restrict__ idxOut, float* __restrict__ part) {
  __shared__ float acc[GV];
  const int tid = threadIdx.x;
  for (int i = tid; i < GV; i += 256) acc[i] = 0.f;
  __syncthreads();
  const int lane = tid & 63;
  const int w = tid >> 6;

#pragma unroll 1
  for (int rr = 0; rr < 16; ++rr) {
    const int r = blockIdx.x * 64 + w * 16 + rr;  // row in [0,4096)
    const int bs = r >> 1, g = r & 1;
    const float* lrow = logits + bs * GV + g * NV;
    const float* grow = gumbels + r * NV;
    float lv[5], av[5];
#pragma unroll
    for (int j = 0; j < 5; ++j) {
      lv[j] = lrow[lane + 64 * j];
      av[j] = lv[j] + grow[lane + 64 * j];
    }
    float m = lv[0];
#pragma unroll
    for (int j = 1; j < 5; ++j) m = fmaxf(m, lv[j]);
#pragma unroll
    for (int o = 32; o > 0; o >>= 1) m = fmaxf(m, __shfl_xor(m, o));
    float e[5];
    float s = 0.f;
#pragma unroll
    for (int j = 0; j < 5; ++j) {
      e[j] = expf(lv[j] - m);
      s += e[j];
    }
#pragma unroll
    for (int o = 32; o > 0; o >>= 1) s += __shfl_xor(s, o);
    const float inv = 1.f / s;
    float bv = av[0];
    int bi = lane;
#pragma unroll
    for (int j = 1; j < 5; ++j) {
      if (av[j] > bv) { bv = av[j]; bi = lane + 64 * j; }
    }
#pragma unroll
    for (int o = 32; o > 0; o >>= 1) {
      float ov = __shfl_xor(bv, o);
      int oi = __shfl_xor(bi, o);
      if (ov > bv || (ov == bv && oi < bi)) { bv = ov; bi = oi; }
    }
    if (lane == 0) idxOut[r] = bi;
#pragma unroll
    for (int j = 0; j < 5; ++j)
      atomicAdd(&acc[g * NV + lane + 64 * j], e[j] * inv);
  }
  __syncthreads();
  for (int i = tid; i < GV; i += 256)
    part[blockIdx.x * GV + i] = acc[i];
}

// ---------------- Gather: out[bs, g*128+d] = codevectors[(g*320+idx[bs,g])*128 + d] --------
__global__ __launch_bounds__(256) void gather_kernel(
    const int* __restrict__ idx, const float* __restrict__ cvs,
    float* __restrict__ out) {
  const int q = blockIdx.x * 256 + threadIdx.x;  // float4 index
  const int f = q << 2;
  const int bs = f >> 8;
  const int rem = f & 255;
  const int g = rem >> 7;
  const int d = rem & 127;
  const int id = idx[(bs << 1) + g];
  const float4 v = *(const float4*)(cvs + (g * NV + id) * DHALF + d);
  *(float4*)(out + f) = v;
}

// ---------------- Perplexity ----------------------------------------------------------------
__global__ __launch_bounds__(256) void perp_kernel(
    const float* __restrict__ part, float* __restrict__ perpOut) {
  __shared__ float colsum[GV];
  const int tid = threadIdx.x;
  for (int i = tid; i < GV; i += 256) {
    float s = 0.f;
    for (int b = 0; b < 64; ++b) s += part[b * GV + i];
    colsum[i] = s;
  }
  __syncthreads();
  float h0 = 0.f, h1 = 0.f;
  for (int i = tid; i < GV; i += 256) {
    const float mmean = colsum[i] * (1.0f / BSROWS);
    const float t = mmean * logf(mmean + 1e-7f);
    if (i < NV) h0 += t; else h1 += t;
  }
  __shared__ float r0[256], r1[256];
  r0[tid] = h0;
  r1[tid] = h1;
  __syncthreads();
  for (int s = 128; s > 0; s >>= 1) {
    if (tid < s) { r0[tid] += r0[tid + s]; r1[tid] += r1[tid + s]; }
    __syncthreads();
  }
  if (tid == 0) perpOut[0] = expf(-r0[0]) + expf(-r1[0]);
}

extern "C" void kernel_launch(void* const* d_in, const int* in_sizes, int n_in,
                              void* d_out, int out_size, void* d_ws, size_t ws_size,
                              hipStream_t stream) {
  const float* x = (const float*)d_in[0];
  const float* W = (const float*)d_in[1];
  const float* b = (const float*)d_in[2];
  const float* cvs = (const float*)d_in[3];
  const float* gum = (const float*)d_in[4];
  float* out = (float*)d_out;

  float* logits = (float*)d_ws;                  // 2048*640 f32
  int* idx = (int*)(logits + BSROWS * GV);       // 4096 i32
  float* part = (float*)(idx + NROWS);           // 64*640 f32
  _Float16* Wth = (_Float16*)(part + 64 * GV);   // 640*512 f16
  _Float16* Wtl = Wth + GV * K_DIM;              // 640*512 f16

  dim3 pgrid(GV / 32, K_DIM / 32);  // (20, 16)
  prep_w_kernel<<<pgrid, 256, 0, stream>>>(W, Wth, Wtl);
  dim3 ggrid(GV / 64, BSROWS / 64);  // (10, 32)
  gemm_mfma_kernel<<<ggrid, 256, 0, stream>>>(x, Wth, Wtl, b, logits);
  row_kernel<<<64, 256, 0, stream>>>(logits, gum, idx, part);
  gather_kernel<<<(BSROWS * 256 / 4) / 256, 256, 0, stream>>>(idx, cvs, out);
  perp_kernel<<<1, 256, 0, stream>>>(part, out + BSROWS * 256);
}

// Round 3
// 55.248 us; speedup vs baseline: 1.4756x; 1.4756x over previous
//
#include <hip/hip_runtime.h>

#define NG 2
#define NV 320
#define GV 640      // NG*NV
#define DHALF 128   // CODE_DIM/NG
#define BSROWS 2048 // B*S
#define NROWS 4096  // BSROWS*NG
#define K_DIM 512
#define NPART 1024  // row-kernel blocks (partials)

typedef _Float16 half8 __attribute__((ext_vector_type(8)));
typedef _Float16 half4 __attribute__((ext_vector_type(4)));
typedef float floatx4 __attribute__((ext_vector_type(4)));

#define MFMA16(a, b, c) __builtin_amdgcn_mfma_f32_16x16x32_f16(a, b, c, 0, 0, 0)

// ---------------- Prep: W[512][640] f32 -> Wt_h/Wt_l [640][512] f16, scale 1024 -----------
__global__ __launch_bounds__(256) void prep_w_kernel(
    const float* __restrict__ W, _Float16* __restrict__ Wth, _Float16* __restrict__ Wtl) {
  __shared__ float T[32][33];
  const int k0 = blockIdx.y * 32, n0 = blockIdx.x * 32;
  const int t = threadIdx.x;
  const int r = t >> 3, c4 = (t & 7) << 2;
  float4 v = *(const float4*)(W + (k0 + r) * GV + n0 + c4);
  T[r][c4 + 0] = v.x; T[r][c4 + 1] = v.y; T[r][c4 + 2] = v.z; T[r][c4 + 3] = v.w;
  __syncthreads();
  const int nr = t >> 3, k4 = (t & 7) << 2;
  half4 hv, lv;
#pragma unroll
  for (int j = 0; j < 4; ++j) {
    float s = T[k4 + j][nr] * 1024.0f;
    _Float16 h = (_Float16)s;
    hv[j] = h;
    lv[j] = (_Float16)(s - (float)h);
  }
  *(half4*)(Wth + (n0 + nr) * K_DIM + k0 + k4) = hv;
  *(half4*)(Wtl + (n0 + nr) * K_DIM + k0 + k4) = lv;
}

// ---------------- GEMM: logits = x @ W + b via f16x2-split MFMA ---------------------------
#define LDAs 40  // f16 per LDS row (32 + 8 pad); 80 B, 16B-aligned

__global__ __launch_bounds__(256) void gemm_mfma_kernel(
    const float* __restrict__ X, const _Float16* __restrict__ Wth,
    const _Float16* __restrict__ Wtl, const float* __restrict__ bias,
    float* __restrict__ C) {
  __shared__ _Float16 Ah[64 * LDAs], Al[64 * LDAs], Bh[64 * LDAs], Bl[64 * LDAs];
  const int tid = threadIdx.x;
  const int bm = blockIdx.y * 64, bn = blockIdx.x * 64;
  const int w = tid >> 6, lane = tid & 63;
  const int wr = w >> 1, wc = w & 1;

  const int srow = tid >> 2;
  const int skc = (tid & 3) << 3;
  const float* Xg = X + (bm + srow) * K_DIM + skc;
  const _Float16* Bhg = Wth + (bn + srow) * K_DIM + skc;
  const _Float16* Blg = Wtl + (bn + srow) * K_DIM + skc;
  const int sA = srow * LDAs + skc;

  const int frow = lane & 15;
  const int fkg = (lane >> 4) << 3;
  const int a0o = (wr * 32 + frow) * LDAs + fkg;
  const int b0o = (wc * 32 + frow) * LDAs + fkg;

  floatx4 acc[2][2] = {};

  for (int k0 = 0; k0 < K_DIM; k0 += 32) {
    float4 xa = *(const float4*)(Xg + k0);
    float4 xb = *(const float4*)(Xg + k0 + 4);
    half8 bhv = *(const half8*)(Bhg + k0);
    half8 blv = *(const half8*)(Blg + k0);
    __syncthreads();
    float xv[8] = {xa.x, xa.y, xa.z, xa.w, xb.x, xb.y, xb.z, xb.w};
    half8 hv, lv;
#pragma unroll
    for (int j = 0; j < 8; ++j) {
      float s = xv[j] * 64.0f;
      _Float16 h = (_Float16)s;
      hv[j] = h;
      lv[j] = (_Float16)(s - (float)h);
    }
    *(half8*)&Ah[sA] = hv;
    *(half8*)&Al[sA] = lv;
    *(half8*)&Bh[sA] = bhv;
    *(half8*)&Bl[sA] = blv;
    __syncthreads();

    half8 ah0 = *(const half8*)&Ah[a0o];
    half8 ah1 = *(const half8*)&Ah[a0o + 16 * LDAs];
    half8 al0 = *(const half8*)&Al[a0o];
    half8 al1 = *(const half8*)&Al[a0o + 16 * LDAs];
    half8 bh0 = *(const half8*)&Bh[b0o];
    half8 bh1 = *(const half8*)&Bh[b0o + 16 * LDAs];
    half8 bl0 = *(const half8*)&Bl[b0o];
    half8 bl1 = *(const half8*)&Bl[b0o + 16 * LDAs];

    acc[0][0] = MFMA16(ah0, bh0, acc[0][0]);
    acc[0][1] = MFMA16(ah0, bh1, acc[0][1]);
    acc[1][0] = MFMA16(ah1, bh0, acc[1][0]);
    acc[1][1] = MFMA16(ah1, bh1, acc[1][1]);
    acc[0][0] = MFMA16(ah0, bl0, acc[0][0]);
    acc[0][1] = MFMA16(ah0, bl1, acc[0][1]);
    acc[1][0] = MFMA16(ah1, bl0, acc[1][0]);
    acc[1][1] = MFMA16(ah1, bl1, acc[1][1]);
    acc[0][0] = MFMA16(al0, bh0, acc[0][0]);
    acc[0][1] = MFMA16(al0, bh1, acc[0][1]);
    acc[1][0] = MFMA16(al1, bh0, acc[1][0]);
    acc[1][1] = MFMA16(al1, bh1, acc[1][1]);
  }

  const float inv = 1.0f / 65536.0f;
#pragma unroll
  for (int i = 0; i < 2; ++i)
#pragma unroll
    for (int j = 0; j < 2; ++j) {
      const int col = bn + wc * 32 + j * 16 + (lane & 15);
      const int r0 = bm + wr * 32 + i * 16 + ((lane >> 4) << 2);
      const float bb = bias[col];
#pragma unroll
      for (int q = 0; q < 4; ++q)
        C[(r0 + q) * GV + col] = acc[i][j][q] * inv + bb;
    }
}

// ---------------- Row kernel: 1 row per wave; fused gather; per-block partial marginals ----
__global__ __launch_bounds__(256) void row_kernel(
    const float* __restrict__ logits, const float* __restrict__ gumbels,
    const float* __restrict__ cvs, float* __restrict__ out,
    float* __restrict__ part) {
  __shared__ float accW[4][NV];
  const int tid = threadIdx.x;
  const int lane = tid & 63;
  const int w = tid >> 6;
  const int r = blockIdx.x * 4 + w;  // row in [0,4096)
  const int bs = r >> 1, g = r & 1;
  const float* lrow = logits + bs * GV + g * NV;
  const float* grow = gumbels + r * NV;

  float lv[5], av[5];
#pragma unroll
  for (int j = 0; j < 5; ++j) {
    lv[j] = lrow[lane + 64 * j];
    av[j] = lv[j] + grow[lane + 64 * j];
  }
  // softmax of raw logits
  float m = lv[0];
#pragma unroll
  for (int j = 1; j < 5; ++j) m = fmaxf(m, lv[j]);
#pragma unroll
  for (int o = 32; o > 0; o >>= 1) m = fmaxf(m, __shfl_xor(m, o));
  float e[5];
  float s = 0.f;
#pragma unroll
  for (int j = 0; j < 5; ++j) {
    e[j] = expf(lv[j] - m);
    s += e[j];
  }
#pragma unroll
  for (int o = 32; o > 0; o >>= 1) s += __shfl_xor(s, o);
  const float inv = 1.f / s;
#pragma unroll
  for (int j = 0; j < 5; ++j) accW[w][lane + 64 * j] = e[j] * inv;

  // argmax of l+gumbel (first-index tie-break); all lanes converge to same bi
  float bv = av[0];
  int bi = lane;
#pragma unroll
  for (int j = 1; j < 5; ++j) {
    if (av[j] > bv) { bv = av[j]; bi = lane + 64 * j; }
  }
#pragma unroll
  for (int o = 32; o > 0; o >>= 1) {
    float ov = __shfl_xor(bv, o);
    int oi = __shfl_xor(bi, o);
    if (ov > bv || (ov == bv && oi < bi)) { bv = ov; bi = oi; }
  }

  // fused gather: out[bs, g*128 + d] = codevectors[(g*320+bi)*128 + d]
  const float2 cv = *(const float2*)(cvs + (g * NV + bi) * DHALF + lane * 2);
  *(float2*)(out + bs * 256 + g * DHALF + lane * 2) = cv;

  // combine 4 waves' softmax -> per-block partial (waves 0,2 = group0; 1,3 = group1)
  __syncthreads();
  for (int i = tid; i < GV; i += 256) {
    float v = (i < NV) ? (accW[0][i] + accW[2][i]) : (accW[1][i - NV] + accW[3][i - NV]);
    part[blockIdx.x * GV + i] = v;
  }
}

// ---------------- Reduce partials: marg[col] = sum_b part[b][col] --------------------------
__global__ __launch_bounds__(256) void reduce_kernel(
    const float* __restrict__ part, float* __restrict__ marg) {
  const int t = threadIdx.x, lane = t & 63, w = t >> 6;
  const int col = blockIdx.x * 64 + lane;
  float s0 = 0.f, s1 = 0.f, s2 = 0.f, s3 = 0.f;
  for (int b = w; b < NPART; b += 16) {
    s0 += part[(b + 0) * GV + col];
    s1 += part[(b + 4) * GV + col];
    s2 += part[(b + 8) * GV + col];
    s3 += part[(b + 12) * GV + col];
  }
  __shared__ float red[4][64];
  red[w][lane] = (s0 + s1) + (s2 + s3);
  __syncthreads();
  if (w == 0)
    marg[blockIdx.x * 64 + lane] = red[0][lane] + red[1][lane] + red[2][lane] + red[3][lane];
}

// ---------------- Perplexity ----------------------------------------------------------------
__global__ __launch_bounds__(256) void perp_kernel(
    const float* __restrict__ marg, float* __restrict__ perpOut) {
  const int tid = threadIdx.x;
  float h0 = 0.f, h1 = 0.f;
  for (int i = tid; i < GV; i += 256) {
    const float mmean = marg[i] * (1.0f / BSROWS);
    const float t = mmean * logf(mmean + 1e-7f);
    if (i < NV) h0 += t; else h1 += t;
  }
  __shared__ float r0[256], r1[256];
  r0[tid] = h0;
  r1[tid] = h1;
  __syncthreads();
  for (int s = 128; s > 0; s >>= 1) {
    if (tid < s) { r0[tid] += r0[tid + s]; r1[tid] += r1[tid + s]; }
    __syncthreads();
  }
  if (tid == 0) perpOut[0] = expf(-r0[0]) + expf(-r1[0]);
}

extern "C" void kernel_launch(void* const* d_in, const int* in_sizes, int n_in,
                              void* d_out, int out_size, void* d_ws, size_t ws_size,
                              hipStream_t stream) {
  const float* x = (const float*)d_in[0];
  const float* W = (const float*)d_in[1];
  const float* b = (const float*)d_in[2];
  const float* cvs = (const float*)d_in[3];
  const float* gum = (const float*)d_in[4];
  float* out = (float*)d_out;

  float* logits = (float*)d_ws;                     // 2048*640 f32
  float* part = logits + BSROWS * GV;               // 1024*640 f32
  float* marg = part + NPART * GV;                  // 640 f32
  _Float16* Wth = (_Float16*)(marg + GV);           // 640*512 f16
  _Float16* Wtl = Wth + GV * K_DIM;                 // 640*512 f16

  dim3 pgrid(GV / 32, K_DIM / 32);  // (20, 16)
  prep_w_kernel<<<pgrid, 256, 0, stream>>>(W, Wth, Wtl);
  dim3 ggrid(GV / 64, BSROWS / 64);  // (10, 32)
  gemm_mfma_kernel<<<ggrid, 256, 0, stream>>>(x, Wth, Wtl, b, logits);
  row_kernel<<<NROWS / 4, 256, 0, stream>>>(logits, gum, cvs, out, part);
  reduce_kernel<<<GV / 64, 256, 0, stream>>>(part, marg);
  perp_kernel<<<1, 256, 0, stream>>>(marg, out + BSROWS * 256);
}